// Round 3
// baseline (834.666 us; speedup 1.0000x reference)
//
#include <hip/hip_runtime.h>
#include <hip/hip_bf16.h>
#include <cstdint>
#include <cstddef>

#define NEXP  8
#define NTOK  4096
#define HID   1024
#define INTER 3584
#define CAP   2048   // per-expert cap == reference jnp.nonzero(size=seq_len)

#define BM  256
#define BN  128
#define BK  32

typedef __attribute__((ext_vector_type(4))) float floatx4;
typedef __attribute__((ext_vector_type(8))) short shortx8;
typedef unsigned short u16;
typedef unsigned int   u32;

__device__ __forceinline__ u16 f2bf(float f) {
    union { float f; unsigned u; } v; v.f = f;
    unsigned r = v.u + 0x7fffu + ((v.u >> 16) & 1u);   // RNE
    return (u16)(r >> 16);
}

__device__ __forceinline__ shortx8 pack8(const float* v) {
    shortx8 r;
#pragma unroll
    for (int i = 0; i < 8; ++i) r[i] = (short)f2bf(v[i]);
    return r;
}

// async global->LDS, 16B per lane. LDS dest = wave-uniform base + lane*16.
__device__ __forceinline__ void async_ld16(const void* g, void* l) {
    __builtin_amdgcn_global_load_lds(
        (const __attribute__((address_space(1))) unsigned int*)g,
        (__attribute__((address_space(3))) unsigned int*)l, 16, 0, 0);
}

// ---------------- routing: per-expert token lists + inverse index ----------------
__global__ void route_kernel(const int* __restrict__ mask, const float* __restrict__ rw,
                             int* __restrict__ cnt, int* __restrict__ list,
                             float* __restrict__ wgt, int* __restrict__ slot) {
    int t = blockIdx.x * blockDim.x + threadIdx.x;
    if (t >= NTOK) return;
#pragma unroll
    for (int e = 0; e < NEXP; ++e) {
#pragma unroll
        for (int k = 0; k < 2; ++k) {
            if (mask[(e * 2 + k) * NTOK + t] != 0) {
                int pos = atomicAdd(&cnt[e], 1);
                if (pos < CAP) {
                    list[e * CAP + pos] = t;
                    wgt[e * CAP + pos] = rw[t * 2 + k];
                    slot[t * 2 + k] = e * CAP + pos;
                } else {
                    slot[t * 2 + k] = -1;   // reference truncation: contribution dropped
                }
            }
        }
    }
}

// ---------------- X: fp32 -> bf16, same layout ----------------
__global__ void xcvt_kernel(const float* __restrict__ X, u16* __restrict__ Xb) {
    const int i = (blockIdx.x * 256 + threadIdx.x) * 8;
    float4 a = *(const float4*)&X[i];
    float4 b = *(const float4*)&X[i + 4];
    float v[8] = {a.x, a.y, a.z, a.w, b.x, b.y, b.z, b.w};
    *(shortx8*)&Xb[i] = pack8(v);
}

// ---------------- W: [K][N] fp32 -> [N][K] bf16, u32-packed LDS transpose ----------------
// 64x64 tile per block. Phase 1: thread reads 2 k-rows x 4 n, packs k-pairs into u32,
// 4 ds_write_b32 (stride 33 -> <=2-way banks, free). Phase 2: 4 scalar u32 reads per
// row-chunk (<=2-way), 16B global store (128B contiguous per row across 8 lanes).
__device__ __forceinline__ void tcvt_tile(const float* __restrict__ src, u16* __restrict__ dst,
                                          int K, int N, int n0, int k0, u32* ldsT, int t) {
    const int nc  = t & 15;
    const int kp0 = t >> 4;
#pragma unroll
    for (int it = 0; it < 2; ++it) {
        const int kp = kp0 + it * 16;
        const int k  = kp * 2;
        const float* s0 = src + (size_t)(k0 + k) * N + n0 + nc * 4;
        float4 f0 = *(const float4*)s0;
        float4 f1 = *(const float4*)(s0 + N);
        ldsT[(nc * 4 + 0) * 33 + kp] = (u32)f2bf(f0.x) | ((u32)f2bf(f1.x) << 16);
        ldsT[(nc * 4 + 1) * 33 + kp] = (u32)f2bf(f0.y) | ((u32)f2bf(f1.y) << 16);
        ldsT[(nc * 4 + 2) * 33 + kp] = (u32)f2bf(f0.z) | ((u32)f2bf(f1.z) << 16);
        ldsT[(nc * 4 + 3) * 33 + kp] = (u32)f2bf(f0.w) | ((u32)f2bf(f1.w) << 16);
    }
    __syncthreads();
    const int rr = t >> 3;
    const int c  = t & 7;
#pragma unroll
    for (int it = 0; it < 2; ++it) {
        const int n = rr + it * 32;
        const u32* p = &ldsT[n * 33 + c * 4];
        u32 v0 = p[0], v1 = p[1], v2 = p[2], v3 = p[3];
        u32* d = (u32*)&dst[(size_t)(n0 + n) * K + k0 + c * 8];
        d[0] = v0; d[1] = v1; d[2] = v2; d[3] = v3;
    }
}

// fused w1+w3: z = e*2 + which
__global__ __launch_bounds__(256)
void tcvt13_kernel(const float* __restrict__ w1, const float* __restrict__ w3,
                   u16* __restrict__ W1b, u16* __restrict__ W3b) {
    __shared__ u32 ldsT[64 * 33];
    const int z = blockIdx.z;
    const int e = z >> 1;
    const float* src = ((z & 1) ? w3 : w1) + (size_t)e * HID * INTER;
    u16*         dst = ((z & 1) ? W3b : W1b) + (size_t)e * HID * INTER;
    tcvt_tile(src, dst, HID, INTER, blockIdx.x * 64, blockIdx.y * 64, ldsT, threadIdx.x);
}

__global__ __launch_bounds__(256)
void tcvt2_kernel(const float* __restrict__ w2, u16* __restrict__ W2b) {
    __shared__ u32 ldsT[64 * 33];
    const int e = blockIdx.z;
    tcvt_tile(w2 + (size_t)e * INTER * HID, W2b + (size_t)e * INTER * HID,
              INTER, HID, blockIdx.x * 64, blockIdx.y * 64, ldsT, threadIdx.x);
}

// ---------------- GEMM1: H = silu(X w1) * (X w3) * rw, bf16 out ----------------
// 512 threads, BM=256, BN=128. Flat grid, XCD-aware remap: all m-blocks of one
// (n,e) weight tile land on one XCD -> weight tile stays L2-resident.
__global__ __launch_bounds__(512, 2)
void gemm1_kernel(const u16* __restrict__ Xb, const u16* __restrict__ W1b,
                  const u16* __restrict__ W3b, const int* __restrict__ cnt,
                  const int* __restrict__ list, const float* __restrict__ wgt,
                  u16* __restrict__ H) {
    // decode: f = xcd + 8*(mb + 8*p); pair = xcd*28 + p -> (nb, e)
    const int f = blockIdx.x;
    const int xcd = f & 7;
    const int u   = f >> 3;
    const int mb  = u & 7;
    const int p   = u >> 3;             // 0..27
    const int pair = xcd * 28 + p;      // 0..223
    const int nb  = pair % 28;
    const int e   = pair / 28;
    const int ce  = min(cnt[e], CAP);
    const int m0  = mb * BM;
    if (m0 >= ce) return;
    const int n0  = nb * BN;

    __shared__ u16 lA [BM * BK];   // 16 KB
    __shared__ u16 lB1[BN * BK];   // 8 KB
    __shared__ u16 lB3[BN * BK];   // 8 KB

    const int tid  = threadIdx.x;
    const int lane = tid & 63;
    const int wave = tid >> 6;     // 0..7
    const int rsub = lane >> 2;    // 0..15
    const int scol = (lane & 3) * 8;

    // A staging: 2 chunks/thread -> rows wave*32 + {0,16} + rsub
    const int arow0 = wave * 32 + rsub;
    const int aoff0 = wave * 1024 + lane * 8;
    const int aoff1 = aoff0 + 512;
    const int t0 = list[e * CAP + min(m0 + arow0, ce - 1)];
    const int t1 = list[e * CAP + min(m0 + arow0 + 16, ce - 1)];
    const u16* ap0 = Xb + (size_t)t0 * HID + scol;
    const u16* ap1 = Xb + (size_t)t1 * HID + scol;
    // B staging: 1 chunk/thread -> row wave*16 + rsub
    const int brow = wave * 16 + rsub;
    const int boff = wave * 512 + lane * 8;
    const u16* b1p = W1b + ((size_t)e * INTER + n0 + brow) * HID + scol;
    const u16* b3p = W3b + ((size_t)e * INTER + n0 + brow) * HID + scol;

    const int fl = lane & 15, fq = lane >> 4;
    const int wm  = (wave >> 1) * 64;   // 0/64/128/192
    const int wnn = (wave & 1) * 64;    // 0/64

    floatx4 acc1[4][4], acc3[4][4];
#pragma unroll
    for (int i = 0; i < 4; ++i)
#pragma unroll
        for (int j = 0; j < 4; ++j)
#pragma unroll
            for (int r = 0; r < 4; ++r) { acc1[i][j][r] = 0.f; acc3[i][j][r] = 0.f; }

    for (int k0 = 0; k0 < HID; k0 += BK) {
        __syncthreads();
        async_ld16(ap0 + k0, &lA [aoff0]);
        async_ld16(ap1 + k0, &lA [aoff1]);
        async_ld16(b1p + k0, &lB1[boff]);
        async_ld16(b3p + k0, &lB3[boff]);
        __syncthreads();

        shortx8 af[4], b1f[4], b3f[4];
#pragma unroll
        for (int i = 0; i < 4; ++i)
            af[i] = *(const shortx8*)&lA[(wm + i * 16 + fl) * BK + fq * 8];
#pragma unroll
        for (int j = 0; j < 4; ++j) {
            b1f[j] = *(const shortx8*)&lB1[(wnn + j * 16 + fl) * BK + fq * 8];
            b3f[j] = *(const shortx8*)&lB3[(wnn + j * 16 + fl) * BK + fq * 8];
        }
#pragma unroll
        for (int i = 0; i < 4; ++i)
#pragma unroll
            for (int j = 0; j < 4; ++j) {
                acc1[i][j] = __builtin_amdgcn_mfma_f32_16x16x32_bf16(af[i], b1f[j], acc1[i][j], 0, 0, 0);
                acc3[i][j] = __builtin_amdgcn_mfma_f32_16x16x32_bf16(af[i], b3f[j], acc3[i][j], 0, 0, 0);
            }
    }

#pragma unroll
    for (int i = 0; i < 4; ++i) {
        const int rowb = m0 + wm + i * 16 + fq * 4;
#pragma unroll
        for (int r = 0; r < 4; ++r) {
            const int row = rowb + r;
            const bool valid = row < ce;
            const float rwv = valid ? wgt[e * CAP + row] : 0.f;
            u16* hp = H + (size_t)(e * CAP + (valid ? row : 0)) * INTER;
#pragma unroll
            for (int j = 0; j < 4; ++j) {
                const int col = n0 + wnn + j * 16 + fl;
                float h1 = acc1[i][j][r];
                float h3 = acc3[i][j][r];
                float sv = h1 / (1.f + __expf(-h1)) * h3 * rwv;
                if (valid) hp[col] = f2bf(sv);
            }
        }
    }
}

// ---------------- GEMM2: part[slot] = H w2 (plain stores, no atomics) ----------------
__global__ __launch_bounds__(512, 2)
void gemm2_kernel(const u16* __restrict__ H, const u16* __restrict__ W2b,
                  const int* __restrict__ cnt, float* __restrict__ part) {
    const int f = blockIdx.x;
    const int xcd = f & 7;
    const int u   = f >> 3;
    const int mb  = u & 7;
    const int p   = u >> 3;            // 0..7
    const int pair = xcd * 8 + p;      // 0..63
    const int nb  = pair & 7;
    const int e   = pair >> 3;
    const int ce  = min(cnt[e], CAP);
    const int m0  = mb * BM;
    if (m0 >= ce) return;
    const int n0  = nb * BN;

    __shared__ u16 lA[BM * BK];   // 16 KB
    __shared__ u16 lB[BN * BK];   // 8 KB

    const int tid  = threadIdx.x;
    const int lane = tid & 63;
    const int wave = tid >> 6;
    const int rsub = lane >> 2;
    const int scol = (lane & 3) * 8;

    const int arow0 = wave * 32 + rsub;
    const int aoff0 = wave * 1024 + lane * 8;
    const int aoff1 = aoff0 + 512;
    // rows >= ce read poison; masked in epilogue
    const u16* ap0 = H + (size_t)(e * CAP + m0 + arow0) * INTER + scol;
    const u16* ap1 = ap0 + (size_t)16 * INTER;
    const int brow = wave * 16 + rsub;
    const int boff = wave * 512 + lane * 8;
    const u16* bp = W2b + ((size_t)e * HID + n0 + brow) * INTER + scol;

    const int fl = lane & 15, fq = lane >> 4;
    const int wm  = (wave >> 1) * 64;
    const int wnn = (wave & 1) * 64;

    floatx4 acc[4][4];
#pragma unroll
    for (int i = 0; i < 4; ++i)
#pragma unroll
        for (int j = 0; j < 4; ++j)
#pragma unroll
            for (int r = 0; r < 4; ++r) acc[i][j][r] = 0.f;

    for (int k0 = 0; k0 < INTER; k0 += BK) {
        __syncthreads();
        async_ld16(ap0 + k0, &lA[aoff0]);
        async_ld16(ap1 + k0, &lA[aoff1]);
        async_ld16(bp  + k0, &lB[boff]);
        __syncthreads();

        shortx8 af[4], bf[4];
#pragma unroll
        for (int i = 0; i < 4; ++i)
            af[i] = *(const shortx8*)&lA[(wm + i * 16 + fl) * BK + fq * 8];
#pragma unroll
        for (int j = 0; j < 4; ++j)
            bf[j] = *(const shortx8*)&lB[(wnn + j * 16 + fl) * BK + fq * 8];
#pragma unroll
        for (int i = 0; i < 4; ++i)
#pragma unroll
            for (int j = 0; j < 4; ++j)
                acc[i][j] = __builtin_amdgcn_mfma_f32_16x16x32_bf16(af[i], bf[j], acc[i][j], 0, 0, 0);
    }

#pragma unroll
    for (int i = 0; i < 4; ++i) {
        const int rowb = m0 + wm + i * 16 + fq * 4;
#pragma unroll
        for (int r = 0; r < 4; ++r) {
            const int row = rowb + r;
            const bool valid = row < ce;
            float* pp = part + (size_t)(e * CAP + row) * HID;
#pragma unroll
            for (int j = 0; j < 4; ++j) {
                const int col = n0 + wnn + j * 16 + fl;
                if (valid) pp[col] = acc[i][j][r];
            }
        }
    }
}

// ---------------- combine: out[t] = part[slot[t,0]] + part[slot[t,1]] ----------------
__global__ void combine_kernel(const float* __restrict__ part, const int* __restrict__ slot,
                               float* __restrict__ out) {
    const int gid = blockIdx.x * 256 + threadIdx.x;     // NTOK*256 threads
    const int t = gid >> 8;
    const int h = (gid & 255) * 4;
    const int s0 = slot[t * 2];
    const int s1 = slot[t * 2 + 1];
    float4 r = make_float4(0.f, 0.f, 0.f, 0.f);
    if (s0 >= 0) {
        float4 a = *(const float4*)&part[(size_t)s0 * HID + h];
        r.x += a.x; r.y += a.y; r.z += a.z; r.w += a.w;
    }
    if (s1 >= 0) {
        float4 b = *(const float4*)&part[(size_t)s1 * HID + h];
        r.x += b.x; r.y += b.y; r.z += b.z; r.w += b.w;
    }
    *(float4*)&out[(size_t)t * HID + h] = r;
}

extern "C" void kernel_launch(void* const* d_in, const int* in_sizes, int n_in,
                              void* d_out, int out_size, void* d_ws, size_t ws_size,
                              hipStream_t stream) {
    const int*   mask = (const int*)  d_in[0];
    const float* X    = (const float*)d_in[1];
    const float* rw   = (const float*)d_in[2];
    const float* w1   = (const float*)d_in[3];
    const float* w2   = (const float*)d_in[4];
    const float* w3   = (const float*)d_in[5];
    float* out = (float*)d_out;

    char* ws = (char*)d_ws;
    size_t off = 0;
    int*   cnt  = (int*)(ws + off);   off += 256;
    int*   list = (int*)(ws + off);   off += (size_t)NEXP * CAP * 4;       // 64 KB
    float* wgt  = (float*)(ws + off); off += (size_t)NEXP * CAP * 4;       // 64 KB
    int*   slot = (int*)(ws + off);   off += (size_t)NTOK * 2 * 4;         // 32 KB
    u16*   Xb   = (u16*)(ws + off);   off += (size_t)NTOK * HID * 2;       // 8 MB
    u16*   W1b  = (u16*)(ws + off);   off += (size_t)NEXP * HID * INTER * 2;   // 56 MB
    u16*   W3b  = (u16*)(ws + off);   off += (size_t)NEXP * HID * INTER * 2;   // 56 MB
    u16*   W2b  = (u16*)(ws + off);   off += (size_t)NEXP * HID * INTER * 2;   // 56 MB
    u16*   H    = (u16*)(ws + off);   off += (size_t)NEXP * CAP * INTER * 2;   // 112 MB
    // part (64 MB) overlays W1b/W3b -- dead after gemm1, stream-ordered before gemm2.
    float* part = (float*)W1b;

    hipMemsetAsync(cnt, 0, 256, stream);

    route_kernel<<<dim3((NTOK + 255) / 256), dim3(256), 0, stream>>>(mask, rw, cnt, list, wgt, slot);
    xcvt_kernel<<<dim3(NTOK * HID / (256 * 8)), dim3(256), 0, stream>>>(X, Xb);
    // w1/w3: [e][HID][INTER] -> [e][INTER][HID]
    tcvt13_kernel<<<dim3(INTER / 64, HID / 64, NEXP * 2), dim3(256), 0, stream>>>(w1, w3, W1b, W3b);
    // w2: [e][INTER][HID] -> [e][HID][INTER]
    tcvt2_kernel<<<dim3(HID / 64, INTER / 64, NEXP), dim3(256), 0, stream>>>(w2, W2b);

    gemm1_kernel<<<dim3(NEXP * (INTER / BN) * (CAP / BM)), dim3(512), 0, stream>>>(
        Xb, W1b, W3b, cnt, list, wgt, H);
    gemm2_kernel<<<dim3(NEXP * (HID / BN) * (CAP / BM)), dim3(512), 0, stream>>>(
        H, W2b, cnt, part);
    combine_kernel<<<dim3(NTOK), dim3(256), 0, stream>>>(part, slot, out);
}